// Round 9
// baseline (215.988 us; speedup 1.0000x reference)
//
#include <hip/hip_runtime.h>
#include <hip/hip_bf16.h>
#include <hip/hip_fp8.h>
#include <stdint.h>

// Shapes: b=2, n=5, k=5, q=75, t=196, c=384, s=k*t=980 (padded to 1024/class)
// M per b = 75*196 = 14700 (77 tiles of 192 rows). Outputs: logits[750] ++ cls_logits[750].
// Sim branch: fp8-e4m3 MX-scaled MFMA (scales=1.0); cls branch exact fp32.
//
// Round-18 = Round-17 resubmitted (round-8 bench was an infra failure: "container
// failed twice"; kernel audited — no hang/OOB/decode bug found).
// Round-17: 3 WAVES/SIMD (M=48/wave, depth-2 pipeline) + R16 swizzle kept.
// R16 post-mortem: XCD swizzle cut FETCH 42.5->13.4 MB but dur flat 63.5us -> L2/HBM
// traffic was never the stall. Surviving invariant: per-wave per-k-step wall ~1400 cyc
// across ALL variants (R3 1446 @3.2 waves/SIMD half-MFMA; R13 1402 @2 waves/SIMD);
// matrix busy = waves/SIMD x MFMA-issue/wall (matches 30%/36% measured). Lever: raise
// resident waves while keeping MFMA/k-step high. M=48: A[3][3]=72 + S[2][4]=32 +
// acc 24 + rmax 12 + addr ~16 ~= 160 unified < 170 -> __launch_bounds__(256,3) = 3
// waves/SIMD. Chunk loop unrolled x2 so the depth-2 slot index is compile-time.
// Grid 1540 = 2b x 5cls x 2sh x 77mt, m204-bijective XCD chunking (4x193 + 4x192),
// reuse-ordered w = (b*77+mt)*10 + (cls*2+sh) (A-tile sharers adjacent; per-XCD-chunk
// working set ~3.4MB < 4MB L2).

typedef __attribute__((ext_vector_type(8))) int int8v;      // f8f6f4 A/B operand (32 fp8)
typedef __attribute__((ext_vector_type(4))) float f32x4;    // MFMA C/D frag

__device__ __forceinline__ unsigned enc_f(float f) {
    unsigned b = __float_as_uint(f);
    return (b & 0x80000000u) ? ~b : (b | 0x80000000u);
}
__device__ __forceinline__ float dec_f(unsigned u) {
    unsigned b = (u & 0x80000000u) ? (u & 0x7FFFFFFFu) : ~u;
    return __uint_as_float(b);
}

__device__ __forceinline__ unsigned pack4_fp8(float a, float b, float c, float d) {
    int r = __builtin_amdgcn_cvt_pk_fp8_f32(a, b, 0, false);   // bytes 0,1
    r = __builtin_amdgcn_cvt_pk_fp8_f32(c, d, r, true);        // bytes 2,3
    return (unsigned)r;
}

// ---------------- fused prep: norm (16 lanes/row) | proto | init_P ----------------
// Query rows -> fqn row-major [tr][96 words]. Shot rows -> fsnp in FRAGMENT order:
// word addr = bn*98304 + sh*49152 + chunk*3072 + ks*1024 + part*256 + hi*64 + l15*4 + w
// where (per j, lane-l16): ks=j>>1, part=(l16>>2)&1, hi=(j&1)*2+(l16>>3), w=l16&3.
__global__ void prep_kernel(const float* __restrict__ feat_query,
                            const float* __restrict__ feat_shot,
                            const float* __restrict__ x_shot,
                            unsigned* __restrict__ fqn,
                            unsigned* __restrict__ fsnp,
                            float* __restrict__ proto,
                            unsigned* __restrict__ P) {
    const int blk  = blockIdx.x;
    const int tid  = threadIdx.x;
    const int lane = tid & 63;
    const int wv   = tid >> 6;

    if (blk < 2478) {                       // ---- token L2 norm -> fp8, 4 rows/wave ----
        const int tr  = blk * 16 + wv * 4 + (lane >> 4);   // 0..39639
        const int l16 = lane & 15;
        if (tr >= 39640) return;

        const float* row;
        unsigned* o32;
        bool zero = false;
        bool shot = false;
        if (tr < 29400) {
            row = feat_query + (size_t)tr * 384;
            o32 = fqn + (size_t)tr * 96;
        } else {
            const int sp = tr - 29400;          // padded shot row: [bn][1024]
            const int bn = sp >> 10;
            const int s  = sp & 1023;           // col within class block
            row  = feat_shot + ((size_t)bn * 980 + s) * 384;
            zero = (s >= 980);
            shot = true;
            const int shh   = s >> 9;
            const int c     = s & 511;
            const int chunk = c >> 5;
            const int cl    = c & 31;
            o32 = fsnp + (size_t)bn * 98304 + shh * 49152 + chunk * 3072
                       + (cl >> 4) * 512 + (cl & 15) * 4;
        }
        // per-j store index (fragment order for shot, row-major for query)
        int idxs[6];
#pragma unroll
        for (int j = 0; j < 6; ++j)
            idxs[j] = shot ? ((j >> 1) * 1024 + ((l16 >> 2) & 1) * 256
                              + (((j & 1) << 1) + (l16 >> 3)) * 64 + (l16 & 3))
                           : (l16 + 16 * j);

        if (zero) {
#pragma unroll
            for (int j = 0; j < 6; ++j) o32[idxs[j]] = 0u;
            return;
        }
        const float4* rf4 = (const float4*)row;
        float4 v[6];
        float ss = 0.f;
#pragma unroll
        for (int j = 0; j < 6; ++j) {
            v[j] = rf4[l16 + 16 * j];
            ss += v[j].x * v[j].x + v[j].y * v[j].y + v[j].z * v[j].z + v[j].w * v[j].w;
        }
#pragma unroll
        for (int off = 1; off < 16; off <<= 1) ss += __shfl_xor(ss, off, 64);
        const float sc = 1.0f / fmaxf(sqrtf(ss), 1e-8f);
#pragma unroll
        for (int j = 0; j < 6; ++j)
            o32[idxs[j]] = pack4_fp8(v[j].x * sc, v[j].y * sc, v[j].z * sc, v[j].w * sc);
    } else if (blk < 2481) {                // ---- proto = l2norm(mean_k x_shot), fp32 ----
        const int gw = (blk - 2478) * 4 + wv;
        if (gw >= 10) return;
        const float* base = x_shot + (size_t)gw * 5 * 384;
        float v[6];
        float ss = 0.f;
#pragma unroll
        for (int j = 0; j < 6; ++j) {
            float s = 0.f;
#pragma unroll
            for (int kk = 0; kk < 5; ++kk) s += base[kk * 384 + lane + 64 * j];
            s *= 0.2f;
            v[j] = s;
            ss += s * s;
        }
#pragma unroll
        for (int off = 1; off < 64; off <<= 1) ss += __shfl_xor(ss, off, 64);
        const float scale = 1.0f / fmaxf(sqrtf(ss), 1e-12f);
#pragma unroll
        for (int j = 0; j < 6; ++j) proto[(size_t)gw * 384 + lane + 64 * j] = v[j] * scale;
    } else {                                // ---- init P to encoded -inf (0) ----
        const int i = (blk - 2481) * 256 + tid;
        if (i < 147000) P[i] = 0u;
    }
}

// ---------------- fp8 GEMM + row-max: 192 A-rows in regs, B depth-2 pipelined ----------------
// grid = 1540 blocks; 256 thr = 4 waves (48 rows each). XCD-chunked ordering (header).
// No LDS, no barriers. B streams from the fragment-ordered fsnp (coalesced 1KB dwordx4
// loads) through a rolling 2-slot register pipeline; chunk loop unrolled x2 so slot
// indices (kglob&1) are compile-time. 6 MFMA per k-step (3 mi x 2 nf).
__global__ __launch_bounds__(256, 3) void gemm_kernel(const uint8_t* __restrict__ fqn,
                                                      const uint8_t* __restrict__ fsnp,
                                                      unsigned* __restrict__ P) {
    // ---- bijective XCD-chunked decode: 1540 = 4 chunks x 193 + 4 chunks x 192 ----
    const int p   = blockIdx.x;
    const int c   = p & 7;
    const int pos = p >> 3;
    const int w   = (c < 4 ? c * 193 : 772 + (c - 4) * 192) + pos;
    const int b   = w / 770;                // 77 mt x 10 g per b
    const int rem = w - b * 770;
    const int mt  = rem / 10;
    const int g   = rem - mt * 10;
    const int sh  = g & 1;
    const int bc  = b * 5 + (g >> 1);       // b*5+cls
    const int m0  = mt * 192;

    const int tid  = threadIdx.x;
    const int lane = tid & 63;
    const int wv   = tid >> 6;
    const int l15  = lane & 15;
    const int hi   = lane >> 4;

    const uint8_t* Ag = fqn  + (size_t)b * 14700 * 384;
    const uint8_t* Bg = fsnp + (size_t)bc * 393216 + (size_t)sh * 196608;
    const uint8_t* bp = Bg + lane * 16;    // + kglob*4096 + j*1024

    // ---- A fragments -> registers (one-time; wave wv holds rows m0+wv*48 .. +47) ----
    int8v A[3][3];
#pragma unroll
    for (int mi = 0; mi < 3; ++mi) {
        int row = m0 + wv * 48 + mi * 16 + l15;
        row = row < 14700 ? row : 14699;           // clamp; dead rows masked at epilogue
        const uint8_t* pa = Ag + (size_t)row * 384 + hi * 32;
#pragma unroll
        for (int ks = 0; ks < 3; ++ks) {
            const uint4 x = *(const uint4*)(pa + ks * 128);
            const uint4 y = *(const uint4*)(pa + ks * 128 + 16);
            A[mi][ks] = (int8v){(int)x.x, (int)x.y, (int)x.z, (int)x.w,
                                (int)y.x, (int)y.y, (int)y.z, (int)y.w};
        }
    }

    float rmax[3][4];
#pragma unroll
    for (int mi = 0; mi < 3; ++mi)
#pragma unroll
        for (int i = 0; i < 4; ++i) rmax[mi][i] = -3.0e38f;

    // ---- prologue: fill the 2-slot pipeline with k-steps 0,1 ----
    uint4 S[2][4];                          // statically indexed only
#pragma unroll
    for (int sl = 0; sl < 2; ++sl) {
        const uint8_t* p2 = bp + (size_t)sl * 4096;
#pragma unroll
        for (int j = 0; j < 4; ++j)
            S[sl][j] = *(const uint4*)(p2 + j * 1024);
    }

    // 8 chunk-pairs x 6 k-steps; kglob = cp*6+u, slot = u&1 (compile-time)
    for (int cp = 0; cp < 8; ++cp) {
        f32x4 acc[3][2];
#pragma unroll
        for (int mi = 0; mi < 3; ++mi)
#pragma unroll
            for (int nf = 0; nf < 2; ++nf) acc[mi][nf] = (f32x4){0.f, 0.f, 0.f, 0.f};

#pragma unroll
        for (int u = 0; u < 6; ++u) {
            constexpr int SLOT_LUT[6] = {0, 1, 0, 1, 0, 1};
            const int sl = SLOT_LUT[u];
            const int8v Bf0 = (int8v){(int)S[sl][0].x, (int)S[sl][0].y,
                                      (int)S[sl][0].z, (int)S[sl][0].w,
                                      (int)S[sl][1].x, (int)S[sl][1].y,
                                      (int)S[sl][1].z, (int)S[sl][1].w};
            const int8v Bf1 = (int8v){(int)S[sl][2].x, (int)S[sl][2].y,
                                      (int)S[sl][2].z, (int)S[sl][2].w,
                                      (int)S[sl][3].x, (int)S[sl][3].y,
                                      (int)S[sl][3].z, (int)S[sl][3].w};
            const int ks = (u < 3) ? u : u - 3;    // A k-slice within the 384-K (per chunk)
#pragma unroll
            for (int mi = 0; mi < 3; ++mi) {
                acc[mi][0] = __builtin_amdgcn_mfma_scale_f32_16x16x128_f8f6f4(
                    A[mi][ks], Bf0, acc[mi][0],
                    0, 0, 0, 0x7F7F7F7F, 0, 0x7F7F7F7F);
                acc[mi][1] = __builtin_amdgcn_mfma_scale_f32_16x16x128_f8f6f4(
                    A[mi][ks], Bf1, acc[mi][1],
                    0, 0, 0, 0x7F7F7F7F, 0, 0x7F7F7F7F);
            }
            // re-issue slot sl for kglob+2 (clamped tail; window = 1 k-step)
            {
                const int kn = cp * 6 + u + 2;
                const int kc = kn < 48 ? kn : 47;
                const uint8_t* p2 = bp + (size_t)kc * 4096;
#pragma unroll
                for (int j = 0; j < 4; ++j)
                    S[sl][j] = *(const uint4*)(p2 + j * 1024);
            }
            // fold row-max at chunk boundaries (u=2 -> chunk cp*2, u=5 -> cp*2+1)
            if (u == 2 || u == 5) {
                const int ch = cp * 2 + (u == 5 ? 1 : 0);
#pragma unroll
                for (int nf = 0; nf < 2; ++nf) {
                    if (sh * 512 + ch * 32 + nf * 16 + l15 < 980) {
#pragma unroll
                        for (int mi = 0; mi < 3; ++mi)
#pragma unroll
                            for (int i = 0; i < 4; ++i)
                                rmax[mi][i] = fmaxf(rmax[mi][i], acc[mi][nf][i]);
                    }
                }
                if (u == 2) {
#pragma unroll
                    for (int mi = 0; mi < 3; ++mi)
#pragma unroll
                        for (int nf = 0; nf < 2; ++nf)
                            acc[mi][nf] = (f32x4){0.f, 0.f, 0.f, 0.f};
                }
            }
        }
    }

    // ---- epilogue: max over the 16 col-lanes, then device-scope atomicMax ----
#pragma unroll
    for (int mi = 0; mi < 3; ++mi)
#pragma unroll
        for (int i = 0; i < 4; ++i) {
            float v = rmax[mi][i];
#pragma unroll
            for (int off = 1; off < 16; off <<= 1) v = fmaxf(v, __shfl_xor(v, off, 64));
            if (l15 == 0) {
                const int row = m0 + wv * 48 + mi * 16 + hi * 4 + i;
                if (row < 14700)
                    atomicMax(&P[(size_t)bc * 14700 + row], enc_f(v));
            }
        }
}

// ---------------- fused final: logits (mean over t of row maxima) | cls_logits ----------------
__global__ void final_kernel(const unsigned* __restrict__ P,
                             const float* __restrict__ xq,
                             const float* __restrict__ proto,
                             float* __restrict__ out) {
    const int blk  = blockIdx.x;
    const int tid  = threadIdx.x;
    const int lane = tid & 63;
    const int wv   = tid >> 6;

    if (blk < 188) {                        // ---- logits ----
        const int gw = blk * 4 + wv;        // (b*75+q)*5+n
        if (gw >= 750) return;
        const int n  = gw % 5;
        const int bq = gw / 5;
        const int b  = bq / 75;
        const int q  = bq % 75;
        const unsigned* row = P + (size_t)(b * 5 + n) * 14700 + q * 196;
        float s = 0.f;
        for (int t = lane; t < 196; t += 64) s += dec_f(row[t]);
#pragma unroll
        for (int off = 1; off < 64; off <<= 1) s += __shfl_xor(s, off, 64);
        if (lane == 0) out[gw] = s * (1.0f / 196.0f);
    } else {                                // ---- cls_logits ----
        const int gw = (blk - 188) * 4 + wv;   // b*75+q
        if (gw >= 150) return;
        const float* row = xq + (size_t)gw * 384;
        float u[6];
        float ss = 0.f;
#pragma unroll
        for (int j = 0; j < 6; ++j) { u[j] = row[lane + 64 * j]; ss += u[j] * u[j]; }
#pragma unroll
        for (int off = 1; off < 64; off <<= 1) ss += __shfl_xor(ss, off, 64);
        const float scale = 1.0f / fmaxf(sqrtf(ss), 1e-12f);
#pragma unroll
        for (int j = 0; j < 6; ++j) u[j] *= scale;
        const int b = gw / 75;
        for (int n = 0; n < 5; ++n) {
            const float* p = proto + (size_t)(b * 5 + n) * 384;
            float d = 0.f;
#pragma unroll
            for (int j = 0; j < 6; ++j) d += u[j] * p[lane + 64 * j];
#pragma unroll
            for (int off = 1; off < 64; off <<= 1) d += __shfl_xor(d, off, 64);
            if (lane == 0) out[750 + gw * 5 + n] = 10.0f * d;
        }
    }
}

extern "C" void kernel_launch(void* const* d_in, const int* in_sizes, int n_in,
                              void* d_out, int out_size, void* d_ws, size_t ws_size,
                              hipStream_t stream) {
    const float* feat_shot  = (const float*)d_in[0];  // [2,5,5,196,384]
    const float* feat_query = (const float*)d_in[1];  // [2,75,196,384]
    const float* x_shot     = (const float*)d_in[2];  // [2,5,5,384]
    const float* x_query    = (const float*)d_in[3];  // [2,75,384]
    float* out = (float*)d_out;
    char* ws = (char*)d_ws;

    // ws layout (15.8 MiB total)
    uint8_t*  fqn   = (uint8_t*)ws;                     // 29400*384  = 11,289,600 B (fp8, row-major)
    uint8_t*  fsnp  = (uint8_t*)(ws + 11289600);        // 10240*384  =  3,932,160 B (fp8, FRAGMENT order)
    float*    proto = (float*)(ws + 15221760);          //      3,840 f32
    unsigned* P     = (unsigned*)(ws + 15237120);       //    147,000 u32

    prep_kernel<<<3056, 256, 0, stream>>>(feat_query, feat_shot, x_shot,
                                          (unsigned*)fqn, (unsigned*)fsnp, proto, P);
    gemm_kernel<<<1540, 256, 0, stream>>>(fqn, fsnp, P);
    final_kernel<<<226, 256, 0, stream>>>(P, x_query, proto, out);
}

// Round 10
// 148.681 us; speedup vs baseline: 1.4527x; 1.4527x over previous
//
#include <hip/hip_runtime.h>
#include <hip/hip_bf16.h>
#include <hip/hip_fp8.h>
#include <stdint.h>

// Shapes: b=2, n=5, k=5, q=75, t=196, c=384, s=k*t=980 (padded to 1024/class)
// M per b = 75*196 = 14700 (46 tiles of 320 rows). Outputs: logits[750] ++ cls_logits[750].
// Sim branch: fp8-e4m3 MX-scaled MFMA (scales=1.0); cls branch exact fp32.
//
// Round-20: M=80/WAVE at 2 waves/SIMD (R13/R16 structure, bigger M-tile).
// R18 post-mortem: launch_bounds(256,3) forced ~170 regs on a ~200-reg working set ->
// spills (WRITE_SIZE 5.7->75MB, VGPR 84, MfmaUtil 17.7%). 3 waves/SIMD is dead.
// Stall model at 2 waves/SIMD: MfmaUtil 36 + VALU 19 = 55% -> both waves stalled ~45%
// of cycles on the per-k-step B-load waitcnt (loaded latency ~300-400 cyc > ~160 cyc
// of own issue work between issue and use). Levers within 2 waves: more MFMA issue
// per k-step + fewer tail rounds -> M=80: 10 MFMA/k-step (busy ~ 2x10x34.6/1400 = 49%),
// same 4KB/wave/k-step B traffic, 920 blocks = 3680 waves = 1.8 rounds (90% fill vs
// 75.5% at M=64). Regs: A[5][3]=120 + S[3][4]=48 + acc 40 + rmax 20 + addr ~16 ~= 248
// <= 256. Spill tripwire = WRITE_SIZE (must stay ~5.7MB).
// XCD swizzle kept (920 = 8 x 115, exact); reuse order w = (b*46+mt)*10 + (cls*2+sh).

typedef __attribute__((ext_vector_type(8))) int int8v;      // f8f6f4 A/B operand (32 fp8)
typedef __attribute__((ext_vector_type(4))) float f32x4;    // MFMA C/D frag

__device__ __forceinline__ unsigned enc_f(float f) {
    unsigned b = __float_as_uint(f);
    return (b & 0x80000000u) ? ~b : (b | 0x80000000u);
}
__device__ __forceinline__ float dec_f(unsigned u) {
    unsigned b = (u & 0x80000000u) ? (u & 0x7FFFFFFFu) : ~u;
    return __uint_as_float(b);
}

__device__ __forceinline__ unsigned pack4_fp8(float a, float b, float c, float d) {
    int r = __builtin_amdgcn_cvt_pk_fp8_f32(a, b, 0, false);   // bytes 0,1
    r = __builtin_amdgcn_cvt_pk_fp8_f32(c, d, r, true);        // bytes 2,3
    return (unsigned)r;
}

// ---------------- fused prep: norm (16 lanes/row) | proto | init_P ----------------
// Query rows -> fqn row-major [tr][96 words]. Shot rows -> fsnp in FRAGMENT order:
// word addr = bn*98304 + sh*49152 + chunk*3072 + ks*1024 + part*256 + hi*64 + l15*4 + w
// where (per j, lane-l16): ks=j>>1, part=(l16>>2)&1, hi=(j&1)*2+(l16>>3), w=l16&3.
__global__ void prep_kernel(const float* __restrict__ feat_query,
                            const float* __restrict__ feat_shot,
                            const float* __restrict__ x_shot,
                            unsigned* __restrict__ fqn,
                            unsigned* __restrict__ fsnp,
                            float* __restrict__ proto,
                            unsigned* __restrict__ P) {
    const int blk  = blockIdx.x;
    const int tid  = threadIdx.x;
    const int lane = tid & 63;
    const int wv   = tid >> 6;

    if (blk < 2478) {                       // ---- token L2 norm -> fp8, 4 rows/wave ----
        const int tr  = blk * 16 + wv * 4 + (lane >> 4);   // 0..39639
        const int l16 = lane & 15;
        if (tr >= 39640) return;

        const float* row;
        unsigned* o32;
        bool zero = false;
        bool shot = false;
        if (tr < 29400) {
            row = feat_query + (size_t)tr * 384;
            o32 = fqn + (size_t)tr * 96;
        } else {
            const int sp = tr - 29400;          // padded shot row: [bn][1024]
            const int bn = sp >> 10;
            const int s  = sp & 1023;           // col within class block
            row  = feat_shot + ((size_t)bn * 980 + s) * 384;
            zero = (s >= 980);
            shot = true;
            const int shh   = s >> 9;
            const int c     = s & 511;
            const int chunk = c >> 5;
            const int cl    = c & 31;
            o32 = fsnp + (size_t)bn * 98304 + shh * 49152 + chunk * 3072
                       + (cl >> 4) * 512 + (cl & 15) * 4;
        }
        // per-j store index (fragment order for shot, row-major for query)
        int idxs[6];
#pragma unroll
        for (int j = 0; j < 6; ++j)
            idxs[j] = shot ? ((j >> 1) * 1024 + ((l16 >> 2) & 1) * 256
                              + (((j & 1) << 1) + (l16 >> 3)) * 64 + (l16 & 3))
                           : (l16 + 16 * j);

        if (zero) {
#pragma unroll
            for (int j = 0; j < 6; ++j) o32[idxs[j]] = 0u;
            return;
        }
        const float4* rf4 = (const float4*)row;
        float4 v[6];
        float ss = 0.f;
#pragma unroll
        for (int j = 0; j < 6; ++j) {
            v[j] = rf4[l16 + 16 * j];
            ss += v[j].x * v[j].x + v[j].y * v[j].y + v[j].z * v[j].z + v[j].w * v[j].w;
        }
#pragma unroll
        for (int off = 1; off < 16; off <<= 1) ss += __shfl_xor(ss, off, 64);
        const float sc = 1.0f / fmaxf(sqrtf(ss), 1e-8f);
#pragma unroll
        for (int j = 0; j < 6; ++j)
            o32[idxs[j]] = pack4_fp8(v[j].x * sc, v[j].y * sc, v[j].z * sc, v[j].w * sc);
    } else if (blk < 2481) {                // ---- proto = l2norm(mean_k x_shot), fp32 ----
        const int gw = (blk - 2478) * 4 + wv;
        if (gw >= 10) return;
        const float* base = x_shot + (size_t)gw * 5 * 384;
        float v[6];
        float ss = 0.f;
#pragma unroll
        for (int j = 0; j < 6; ++j) {
            float s = 0.f;
#pragma unroll
            for (int kk = 0; kk < 5; ++kk) s += base[kk * 384 + lane + 64 * j];
            s *= 0.2f;
            v[j] = s;
            ss += s * s;
        }
#pragma unroll
        for (int off = 1; off < 64; off <<= 1) ss += __shfl_xor(ss, off, 64);
        const float scale = 1.0f / fmaxf(sqrtf(ss), 1e-12f);
#pragma unroll
        for (int j = 0; j < 6; ++j) proto[(size_t)gw * 384 + lane + 64 * j] = v[j] * scale;
    } else {                                // ---- init P to encoded -inf (0) ----
        const int i = (blk - 2481) * 256 + tid;
        if (i < 147000) P[i] = 0u;
    }
}

// ---------------- fp8 GEMM + row-max: 320 A-rows in regs, B depth-3 pipelined ----------------
// grid = 920 blocks (8 XCD-chunks x 115); 256 thr = 4 waves (80 rows each).
// No LDS, no barriers. B fragments stream from the fragment-ordered fsnp (coalesced
// 1KB dwordx4 loads) through a rolling 3-slot register pipeline: slot ks holds k-step
// kglob with kglob%3==ks; after the 10 MFMAs of k-step kglob, the slot is re-issued
// for kglob+3 (WAR on the same regs keeps pressure flat; all indices compile-time).
__global__ __launch_bounds__(256, 2) void gemm_kernel(const uint8_t* __restrict__ fqn,
                                                      const uint8_t* __restrict__ fsnp,
                                                      unsigned* __restrict__ P) {
    // ---- XCD-chunked bijective decode: p -> w = (b*46+mt)*10 + (cls*2+sh) ----
    const int p   = blockIdx.x;             // 920 = 8 chunks x 115
    const int w   = (p & 7) * 115 + (p >> 3);
    const int b   = w / 460;                // 46 mt x 10 g per b
    const int rem = w - b * 460;
    const int mt  = rem / 10;
    const int g   = rem - mt * 10;
    const int sh  = g & 1;
    const int bc  = b * 5 + (g >> 1);       // b*5+cls
    const int m0  = mt * 320;

    const int tid  = threadIdx.x;
    const int lane = tid & 63;
    const int wv   = tid >> 6;
    const int l15  = lane & 15;
    const int hi   = lane >> 4;

    const uint8_t* Ag = fqn  + (size_t)b * 14700 * 384;
    const uint8_t* Bg = fsnp + (size_t)bc * 393216 + (size_t)sh * 196608;
    const uint8_t* bp = Bg + lane * 16;    // + kglob*4096 + j*1024

    // ---- A fragments -> registers (one-time; wave wv holds rows m0+wv*80 .. +79) ----
    int8v A[5][3];
#pragma unroll
    for (int mi = 0; mi < 5; ++mi) {
        int row = m0 + wv * 80 + mi * 16 + l15;
        row = row < 14700 ? row : 14699;           // clamp; dead rows masked at epilogue
        const uint8_t* pa = Ag + (size_t)row * 384 + hi * 32;
#pragma unroll
        for (int ks = 0; ks < 3; ++ks) {
            const uint4 x = *(const uint4*)(pa + ks * 128);
            const uint4 y = *(const uint4*)(pa + ks * 128 + 16);
            A[mi][ks] = (int8v){(int)x.x, (int)x.y, (int)x.z, (int)x.w,
                                (int)y.x, (int)y.y, (int)y.z, (int)y.w};
        }
    }

    float rmax[5][4];
#pragma unroll
    for (int mi = 0; mi < 5; ++mi)
#pragma unroll
        for (int i = 0; i < 4; ++i) rmax[mi][i] = -3.0e38f;

    // ---- prologue: fill the 3-slot pipeline with k-steps 0,1,2 ----
    uint4 S[3][4];                          // statically indexed only
#pragma unroll
    for (int ks = 0; ks < 3; ++ks) {
        const uint8_t* p2 = bp + (size_t)ks * 4096;
#pragma unroll
        for (int j = 0; j < 4; ++j)
            S[ks][j] = *(const uint4*)(p2 + j * 1024);
    }

    for (int chunk = 0; chunk < 16; ++chunk) {
        f32x4 acc[5][2];
#pragma unroll
        for (int mi = 0; mi < 5; ++mi)
#pragma unroll
            for (int nf = 0; nf < 2; ++nf) acc[mi][nf] = (f32x4){0.f, 0.f, 0.f, 0.f};

#pragma unroll
        for (int ks = 0; ks < 3; ++ks) {
            // consume slot ks (k-step chunk*3+ks; chunk*3+ks ≡ ks mod 3)
            const int8v Bf0 = (int8v){(int)S[ks][0].x, (int)S[ks][0].y,
                                      (int)S[ks][0].z, (int)S[ks][0].w,
                                      (int)S[ks][1].x, (int)S[ks][1].y,
                                      (int)S[ks][1].z, (int)S[ks][1].w};
            const int8v Bf1 = (int8v){(int)S[ks][2].x, (int)S[ks][2].y,
                                      (int)S[ks][2].z, (int)S[ks][2].w,
                                      (int)S[ks][3].x, (int)S[ks][3].y,
                                      (int)S[ks][3].z, (int)S[ks][3].w};
#pragma unroll
            for (int mi = 0; mi < 5; ++mi) {
                acc[mi][0] = __builtin_amdgcn_mfma_scale_f32_16x16x128_f8f6f4(
                    A[mi][ks], Bf0, acc[mi][0],
                    0, 0, 0, 0x7F7F7F7F, 0, 0x7F7F7F7F);
                acc[mi][1] = __builtin_amdgcn_mfma_scale_f32_16x16x128_f8f6f4(
                    A[mi][ks], Bf1, acc[mi][1],
                    0, 0, 0, 0x7F7F7F7F, 0, 0x7F7F7F7F);
            }
            // re-issue slot ks for k-step chunk*3+ks+3 (clamped tail; issue->use
            // window = 2 full k-steps of MFMA >= loaded L2 latency)
            {
                const int kn = chunk * 3 + ks + 3;
                const int kc = kn < 48 ? kn : 47;
                const uint8_t* p2 = bp + (size_t)kc * 4096;
#pragma unroll
                for (int j = 0; j < 4; ++j)
                    S[ks][j] = *(const uint4*)(p2 + j * 1024);
            }
        }

        // fold row-max (mask padded cols >= 980; only sh=1 late chunks can fail)
#pragma unroll
        for (int nf = 0; nf < 2; ++nf) {
            if (sh * 512 + chunk * 32 + nf * 16 + l15 < 980) {
#pragma unroll
                for (int mi = 0; mi < 5; ++mi)
#pragma unroll
                    for (int i = 0; i < 4; ++i)
                        rmax[mi][i] = fmaxf(rmax[mi][i], acc[mi][nf][i]);
            }
        }
    }

    // ---- epilogue: max over the 16 col-lanes, then device-scope atomicMax ----
#pragma unroll
    for (int mi = 0; mi < 5; ++mi)
#pragma unroll
        for (int i = 0; i < 4; ++i) {
            float v = rmax[mi][i];
#pragma unroll
            for (int off = 1; off < 16; off <<= 1) v = fmaxf(v, __shfl_xor(v, off, 64));
            if (l15 == 0) {
                const int row = m0 + wv * 80 + mi * 16 + hi * 4 + i;
                if (row < 14700)
                    atomicMax(&P[(size_t)bc * 14700 + row], enc_f(v));
            }
        }
}

// ---------------- fused final: logits (mean over t of row maxima) | cls_logits ----------------
__global__ void final_kernel(const unsigned* __restrict__ P,
                             const float* __restrict__ xq,
                             const float* __restrict__ proto,
                             float* __restrict__ out) {
    const int blk  = blockIdx.x;
    const int tid  = threadIdx.x;
    const int lane = tid & 63;
    const int wv   = tid >> 6;

    if (blk < 188) {                        // ---- logits ----
        const int gw = blk * 4 + wv;        // (b*75+q)*5+n
        if (gw >= 750) return;
        const int n  = gw % 5;
        const int bq = gw / 5;
        const int b  = bq / 75;
        const int q  = bq % 75;
        const unsigned* row = P + (size_t)(b * 5 + n) * 14700 + q * 196;
        float s = 0.f;
        for (int t = lane; t < 196; t += 64) s += dec_f(row[t]);
#pragma unroll
        for (int off = 1; off < 64; off <<= 1) s += __shfl_xor(s, off, 64);
        if (lane == 0) out[gw] = s * (1.0f / 196.0f);
    } else {                                // ---- cls_logits ----
        const int gw = (blk - 188) * 4 + wv;   // b*75+q
        if (gw >= 150) return;
        const float* row = xq + (size_t)gw * 384;
        float u[6];
        float ss = 0.f;
#pragma unroll
        for (int j = 0; j < 6; ++j) { u[j] = row[lane + 64 * j]; ss += u[j] * u[j]; }
#pragma unroll
        for (int off = 1; off < 64; off <<= 1) ss += __shfl_xor(ss, off, 64);
        const float scale = 1.0f / fmaxf(sqrtf(ss), 1e-12f);
#pragma unroll
        for (int j = 0; j < 6; ++j) u[j] *= scale;
        const int b = gw / 75;
        for (int n = 0; n < 5; ++n) {
            const float* p = proto + (size_t)(b * 5 + n) * 384;
            float d = 0.f;
#pragma unroll
            for (int j = 0; j < 6; ++j) d += u[j] * p[lane + 64 * j];
#pragma unroll
            for (int off = 1; off < 64; off <<= 1) d += __shfl_xor(d, off, 64);
            if (lane == 0) out[750 + gw * 5 + n] = 10.0f * d;
        }
    }
}

extern "C" void kernel_launch(void* const* d_in, const int* in_sizes, int n_in,
                              void* d_out, int out_size, void* d_ws, size_t ws_size,
                              hipStream_t stream) {
    const float* feat_shot  = (const float*)d_in[0];  // [2,5,5,196,384]
    const float* feat_query = (const float*)d_in[1];  // [2,75,196,384]
    const float* x_shot     = (const float*)d_in[2];  // [2,5,5,384]
    const float* x_query    = (const float*)d_in[3];  // [2,75,384]
    float* out = (float*)d_out;
    char* ws = (char*)d_ws;

    // ws layout (15.8 MiB total)
    uint8_t*  fqn   = (uint8_t*)ws;                     // 29400*384  = 11,289,600 B (fp8, row-major)
    uint8_t*  fsnp  = (uint8_t*)(ws + 11289600);        // 10240*384  =  3,932,160 B (fp8, FRAGMENT order)
    float*    proto = (float*)(ws + 15221760);          //      3,840 f32
    unsigned* P     = (unsigned*)(ws + 15237120);       //    147,000 u32

    prep_kernel<<<3056, 256, 0, stream>>>(feat_query, feat_shot, x_shot,
                                          (unsigned*)fqn, (unsigned*)fsnp, proto, P);
    gemm_kernel<<<920, 256, 0, stream>>>(fqn, fsnp, P);
    final_kernel<<<226, 256, 0, stream>>>(P, x_query, proto, out);
}